// Round 8
// baseline (202.056 us; speedup 1.0000x reference)
//
#include <hip/hip_runtime.h>

#define LN_EPS 1e-5f
#define LOG2E 1.44269504f
#define NHALF_LOG2E (-0.72134752f)

#if __has_builtin(__builtin_amdgcn_exp2f)
#define EXP2F(x) __builtin_amdgcn_exp2f(x)
#else
#define EXP2F(x) __expf((x) * 0.69314718f)
#endif

// Megakernel v5: wav0 -> bar -> lnR0 -> wav1 -> bar -> lnR1 -> wav2 -> bar -> cls.
// R7 analysis: phases ~20us (VALU floor), the other ~60us was 3 serial tail
// regions (bar + 32-block LN + bar; LN part-reads 128B-stride uncoalesced UC).
// This round kills the tails:
//  - part buffer replaced by atomicAdd into hacc[b][o] (64KB, b-major ->
//    coalesced LN reads; host memset zeroes per launch). Atomics execute at
//    the coherence point -> UC reads see them after the vmcnt-drain barrier.
//  - LN done REDUNDANTLY by every block (read 64KB coalesced, per-wave
//    shuffle stats, write only own 64-row slice to LDS h_lds[64][33]).
//    Removes the 32-block serial phases AND 2 of 5 grid barriers.
//  - wav1/2 read h from LDS (2-way bank alias = free) instead of L3.
// Barrier: fence-free (vmcnt drain + relaxed agent atomics), hierarchical.
// Grid 512x512, __launch_bounds__(512,4): LDS ~61KB -> 2 blocks/CU guaranteed.

constexpr int NBLK   = 512;
constexpr int TPB    = 512;
constexpr int NGRP   = 16;
constexpr int GRP    = NBLK / NGRP;         // 32
constexpr int PADX   = 34;                  // x-slab row stride
constexpr int PADH   = 33;                  // h_lds row stride (odd: 2-way max)

// ---------------------------------------------------------------------------
__device__ __forceinline__ float sysld(const float* p)
{
    return __hip_atomic_load(p, __ATOMIC_RELAXED, __HIP_MEMORY_SCOPE_SYSTEM);
}

// ---------------------------------------------------------------------------
__device__ __forceinline__ void gridbar(int* __restrict__ bar, int k)
{
    asm volatile("s_waitcnt vmcnt(0)" ::: "memory");  // atomics/stores drained
    __syncthreads();
    if (threadIdx.x == 0) {
        const int g = blockIdx.x >> 5;
        int* grpArr = bar + g * 32;
        int* grpRel = bar + (NGRP + g) * 32;
        int* gArr   = bar + 2 * NGRP * 32;

        int old = __hip_atomic_fetch_add(grpArr, 1, __ATOMIC_RELAXED,
                                         __HIP_MEMORY_SCOPE_AGENT);
        if (old == k * GRP - 1) {
            int o2 = __hip_atomic_fetch_add(gArr, 1, __ATOMIC_RELAXED,
                                            __HIP_MEMORY_SCOPE_AGENT);
            if (o2 == k * NGRP - 1) {
#pragma unroll
                for (int j = 0; j < NGRP; ++j)
                    __hip_atomic_store(bar + (NGRP + j) * 32, k,
                                       __ATOMIC_RELAXED, __HIP_MEMORY_SCOPE_AGENT);
            }
        }
        while (__hip_atomic_load(grpRel, __ATOMIC_RELAXED,
                                 __HIP_MEMORY_SCOPE_AGENT) < k)
            __builtin_amdgcn_s_sleep(8);
    }
    __syncthreads();
}

// epilogue: spread 32 batch-partials over lanes 0..31, one atomicAdd each.
// hacc layout [b][o] (b-major) so LN reads are coalesced.
__device__ __forceinline__ void acc_atomic(float* __restrict__ hacc, int o,
                                           float acc0, float acc1, int lane)
{
    acc0 += __shfl_down(acc0, 32); acc0 += __shfl_down(acc0, 16);
    acc1 += __shfl_down(acc1, 32); acc1 += __shfl_down(acc1, 16);
    int srcl = (lane < 16) ? lane : (lane - 16);
    float a1 = __shfl(acc1, srcl);
    if (lane < 32) {
        int   b  = (lane < 16) ? (lane << 1) : (((lane - 16) << 1) | 1);
        float av = (lane < 16) ? acc0 : a1;
        atomicAdd(hacc + (size_t)b * 512 + o, av);
    }
}

// ---------------------------------------------------------------------------
// wav0: KIN=6144, S=32 (RANGE=192). si = bid>>4, o-range (bid&15)*32..+32,
// wave does TPW=4 tasks with 1-deep register prefetch of w/t/s rows.
// ---------------------------------------------------------------------------
__device__ __forceinline__ void wav0_phase(const float* __restrict__ x,
        const float* __restrict__ w, const float* __restrict__ t,
        const float* __restrict__ s, float* __restrict__ hacc,
        float4* __restrict__ myPrep, float* __restrict__ xs,
        int lane, int wave)
{
    constexpr int RANGE = 192, STEPS = RANGE / 4, TPW = 4;
    const int si    = blockIdx.x >> 4;
    const int obase = (blockIdx.x & 15) * 32;
    const int ibase = si * RANGE;

    for (int b = wave; b < 32; b += 8)
        for (int i2 = lane; i2 < RANGE; i2 += 64)
            xs[i2 * PADX + b] = x[b * 6144 + ibase + i2];
    __syncthreads();

    const int p = lane & 15, g = lane >> 4;
    const int o0 = obase + wave * TPW;
    const float* __restrict__ wp = w + (size_t)o0 * 6144 + ibase;
    const float* __restrict__ tp = t + (size_t)o0 * 6144 + ibase;
    const float* __restrict__ sp = s + (size_t)o0 * 6144 + ibase;

    float fw[3], ft[3], fs[3];
#pragma unroll
    for (int r = 0; r < 3; ++r) {
        int il = r * 64 + lane;
        fw[r] = wp[il]; ft[r] = tp[il]; fs[r] = sp[il];
    }

#pragma unroll
    for (int ti = 0; ti < TPW; ++ti) {
#pragma unroll
        for (int r = 0; r < 3; ++r) {
            int il = r * 64 + lane;
            float sig = __builtin_amdgcn_rcpf(1.f + EXP2F(-fs[r] * LOG2E));
            float inv = __builtin_amdgcn_rcpf(fmaf(9.99f, sig, 0.01000001f));
            myPrep[il] = make_float4(inv, -ft[r] * inv, fw[r], 0.f);
        }
        if (ti + 1 < TPW) {
            const float* wpn = wp + (size_t)(ti + 1) * 6144;
            const float* tpn = tp + (size_t)(ti + 1) * 6144;
            const float* spn = sp + (size_t)(ti + 1) * 6144;
#pragma unroll
            for (int r = 0; r < 3; ++r) {
                int il = r * 64 + lane;
                fw[r] = wpn[il]; ft[r] = tpn[il]; fs[r] = spn[il];
            }
        }

        float acc0 = 0.f, acc1 = 0.f;
#pragma unroll 8
        for (int st = 0; st < STEPS; ++st) {
            float4 pr = myPrep[st * 4 + g];
            float2 xv = *(const float2*)&xs[(st * 4 + g) * PADX + 2 * p];
            float u0 = fmaf(xv.x, pr.x, pr.y);
            float u1 = fmaf(xv.y, pr.x, pr.y);
            float q0 = u0 * u0, q1 = u1 * u1;
            float e0 = EXP2F(q0 * NHALF_LOG2E);
            float e1 = EXP2F(q1 * NHALF_LOG2E);
            float pw0 = fmaf(-pr.z, q0, pr.z);
            float pw1 = fmaf(-pr.z, q1, pr.z);
            acc0 = fmaf(pw0, e0, acc0);
            acc1 = fmaf(pw1, e1, acc1);
        }
        acc_atomic(hacc, o0 + ti, acc0, acc1, lane);
    }
}

// ---------------------------------------------------------------------------
// Redundant silu+LN: every block. Thread t = row o: reads hacc[b][t]
// (coalesced, UC), silu -> a[32]; per-wave shuffle stats; wave si_blk applies
// LN and writes its 64-row slice into h_lds[row][b] (pad-33).
// ---------------------------------------------------------------------------
__device__ __forceinline__ void ln_red(const float* __restrict__ hacc,
        const float* __restrict__ gam, const float* __restrict__ bet,
        float* __restrict__ h_lds, float (* __restrict__ redS)[32],
        float (* __restrict__ redQ)[32], int si_blk)
{
    const int t = threadIdx.x, lane = t & 63, wid = t >> 6;
    float a[32];
#pragma unroll
    for (int b = 0; b < 32; ++b) {
        float v = sysld(hacc + (size_t)b * 512 + t);
        a[b] = v * __builtin_amdgcn_rcpf(1.f + EXP2F(-v * LOG2E));  // silu
    }
#pragma unroll
    for (int b = 0; b < 32; ++b) {
        float u = a[b], q = a[b] * a[b];
#pragma unroll
        for (int off = 32; off; off >>= 1) {
            u += __shfl_xor(u, off);
            q += __shfl_xor(q, off);
        }
        if (lane == 0) { redS[wid][b] = u; redQ[wid][b] = q; }
    }
    __syncthreads();
    if (wid == si_blk) {                 // this wave's threads own rows si*64..
        const int row = lane;
        float gm = gam[t], bt = bet[t];
#pragma unroll
        for (int b = 0; b < 32; ++b) {
            float t1 = 0.f, t2 = 0.f;
#pragma unroll
            for (int w2 = 0; w2 < 8; ++w2) { t1 += redS[w2][b]; t2 += redQ[w2][b]; }
            float m   = t1 * (1.f / 512.f);
            float var = t2 * (1.f / 512.f) - m * m;
            float r   = __builtin_amdgcn_rsqf(var + LN_EPS);
            h_lds[row * PADH + b] = (a[b] - m) * r * gm + bt;
        }
    }
    __syncthreads();
}

// ---------------------------------------------------------------------------
// wav1/2: RANGE=64, TPW=1 (wave gw -> o=gw&511). h from LDS slice; prep
// params arrive prefetched in registers.
// ---------------------------------------------------------------------------
__device__ __forceinline__ void wav12_phase(const float* __restrict__ h_lds,
        float* __restrict__ hacc, float4* __restrict__ myPrep,
        int lane, int gw, float fw, float ft, float fs)
{
    constexpr int STEPS = 16;
    const int p = lane & 15, g = lane >> 4;
    const int o = gw & 511;

    {
        float sig = __builtin_amdgcn_rcpf(1.f + EXP2F(-fs * LOG2E));
        float inv = __builtin_amdgcn_rcpf(fmaf(9.99f, sig, 0.01000001f));
        myPrep[lane] = make_float4(inv, -ft * inv, fw, 0.f);
    }

    float acc0 = 0.f, acc1 = 0.f;
#pragma unroll 8
    for (int st = 0; st < STEPS; ++st) {
        float4 pr = myPrep[st * 4 + g];
        int row = g + 4 * st;
        float x0 = h_lds[row * PADH + 2 * p];
        float x1 = h_lds[row * PADH + 2 * p + 1];
        float u0 = fmaf(x0, pr.x, pr.y);
        float u1 = fmaf(x1, pr.x, pr.y);
        float q0 = u0 * u0, q1 = u1 * u1;
        float e0 = EXP2F(q0 * NHALF_LOG2E);
        float e1 = EXP2F(q1 * NHALF_LOG2E);
        float pw0 = fmaf(-pr.z, q0, pr.z);
        float pw1 = fmaf(-pr.z, q1, pr.z);
        acc0 = fmaf(pw0, e0, acc0);
        acc1 = fmaf(pw1, e1, acc1);
    }
    acc_atomic(hacc, o, acc0, acc1, lane);
}

// ---------------------------------------------------------------------------
// cls: blocks 0..31 (b = blockIdx), tid = o. hacc read is coalesced ([b][o]).
// ---------------------------------------------------------------------------
__device__ __forceinline__ void cls_phase(const float* __restrict__ hacc,
        const float* __restrict__ gam, const float* __restrict__ bet,
        const float* __restrict__ cw, const float* __restrict__ cb,
        float* __restrict__ out, float* __restrict__ r1, float* __restrict__ r2,
        float (* __restrict__ cr)[8])
{
    if (blockIdx.x < 32) {
        const int b = blockIdx.x, tid = threadIdx.x;
        float v = sysld(hacc + (size_t)b * 512 + tid);
        float a = v * __builtin_amdgcn_rcpf(1.f + EXP2F(-v * LOG2E));

        float s1 = a, s2 = a * a;
#pragma unroll
        for (int off = 32; off; off >>= 1) {
            s1 += __shfl_down(s1, off);
            s2 += __shfl_down(s2, off);
        }
        const int lane = tid & 63, wid = tid >> 6;
        if (lane == 0) { r1[wid] = s1; r2[wid] = s2; }
        __syncthreads();
        float t1 = 0.f, t2 = 0.f;
#pragma unroll
        for (int k = 0; k < 8; ++k) { t1 += r1[k]; t2 += r2[k]; }
        float m   = t1 * (1.f / 512.f);
        float var = t2 * (1.f / 512.f) - m * m;
        float r   = __builtin_amdgcn_rsqf(var + LN_EPS);
        float hl  = (a - m) * r * gam[tid] + bet[tid];

#pragma unroll
        for (int c = 0; c < 5; ++c) {
            float pv = hl * cw[c * 512 + tid];
#pragma unroll
            for (int off = 32; off; off >>= 1) pv += __shfl_down(pv, off);
            if (lane == 0) cr[c][wid] = pv;
        }
        __syncthreads();
        if (tid < 5) {
            float sum = 0.f;
#pragma unroll
            for (int k = 0; k < 8; ++k) sum += cr[tid][k];
            out[b * 5 + tid] = sum + cb[tid];
        }
    }
}

// ---------------------------------------------------------------------------
__global__ __launch_bounds__(TPB, 4)
void megakernel(const float* __restrict__ x,
                const float* __restrict__ w0, const float* __restrict__ t0,
                const float* __restrict__ s0, const float* __restrict__ g0,
                const float* __restrict__ b0,
                const float* __restrict__ w1, const float* __restrict__ t1,
                const float* __restrict__ s1, const float* __restrict__ g1,
                const float* __restrict__ b1,
                const float* __restrict__ w2, const float* __restrict__ t2,
                const float* __restrict__ s2, const float* __restrict__ g2,
                const float* __restrict__ b2,
                const float* __restrict__ cw, const float* __restrict__ cb,
                float* __restrict__ out,
                float* __restrict__ hacc0, float* __restrict__ hacc1,
                float* __restrict__ hacc2, int* __restrict__ bar)
{
    __shared__ float4 prep[8][192];            // 24.6 KiB per-wave prep slabs
    __shared__ float  xs[192 * PADX];          // 26.1 KiB x si-slab [i][b]
    __shared__ float  h_lds[64 * PADH];        // 8.25 KiB LN'd h slice [row][b]
    __shared__ float  redS[8][32], redQ[8][32];// 2 KiB LN reduction
    __shared__ float  r1[8], r2[8], cr[5][8];  // cls scratch

    const int wave = threadIdx.x >> 6, lane = threadIdx.x & 63;
    const int gw = blockIdx.x * (TPB / 64) + wave;
    const int si_blk = blockIdx.x >> 6;        // == gw>>9 for all 8 waves
    float4* myPrep = prep[wave];

    wav0_phase(x, w0, t0, s0, hacc0, myPrep, xs, lane, wave);
    // prefetch layer-1 prep params (land during barrier + lnR0)
    const int o1 = gw & 511;
    const size_t off1 = (size_t)o1 * 512 + si_blk * 64 + lane;
    float fw1 = w1[off1], ft1 = t1[off1], fs1 = s1[off1];
    gridbar(bar, 1);

    ln_red(hacc0, g0, b0, h_lds, redS, redQ, si_blk);
    wav12_phase(h_lds, hacc1, myPrep, lane, gw, fw1, ft1, fs1);
    float fw2 = w2[off1], ft2 = t2[off1], fs2 = s2[off1];
    gridbar(bar, 2);

    ln_red(hacc1, g1, b1, h_lds, redS, redQ, si_blk);
    wav12_phase(h_lds, hacc2, myPrep, lane, gw, fw2, ft2, fs2);
    gridbar(bar, 3);

    cls_phase(hacc2, g2, b2, cw, cb, out, r1, r2, cr);
}

extern "C" void kernel_launch(void* const* d_in, const int* in_sizes, int n_in,
                              void* d_out, int out_size, void* d_ws, size_t ws_size,
                              hipStream_t stream)
{
    const float* x  = (const float*)d_in[0];
    const float* w0 = (const float*)d_in[1];
    const float* t0 = (const float*)d_in[2];
    const float* s0 = (const float*)d_in[3];
    const float* g0 = (const float*)d_in[4];
    const float* b0 = (const float*)d_in[5];
    const float* w1 = (const float*)d_in[6];
    const float* t1 = (const float*)d_in[7];
    const float* s1 = (const float*)d_in[8];
    const float* g1 = (const float*)d_in[9];
    const float* b1 = (const float*)d_in[10];
    const float* w2 = (const float*)d_in[11];
    const float* t2 = (const float*)d_in[12];
    const float* s2 = (const float*)d_in[13];
    const float* g2 = (const float*)d_in[14];
    const float* b2 = (const float*)d_in[15];
    const float* cw = (const float*)d_in[16];
    const float* cb = (const float*)d_in[17];
    float* out = (float*)d_out;

    // ws layout (floats): hacc0 16384 | hacc1 16384 | hacc2 16384 | bar (8KB)
    float* hacc0 = (float*)d_ws;
    float* hacc1 = hacc0 + 16384;
    float* hacc2 = hacc1 + 16384;
    int*   bar   = (int*)(hacc2 + 16384);

    // zero accumulators + barrier (capture-safe single memset, 200KB)
    hipMemsetAsync(d_ws, 0, 3 * 16384 * 4 + 8192, stream);

    void* args[] = { (void*)&x,
                     (void*)&w0, (void*)&t0, (void*)&s0, (void*)&g0, (void*)&b0,
                     (void*)&w1, (void*)&t1, (void*)&s1, (void*)&g1, (void*)&b1,
                     (void*)&w2, (void*)&t2, (void*)&s2, (void*)&g2, (void*)&b2,
                     (void*)&cw, (void*)&cb, (void*)&out,
                     (void*)&hacc0, (void*)&hacc1, (void*)&hacc2, (void*)&bar };

    hipLaunchKernel((const void*)megakernel, dim3(NBLK), dim3(TPB),
                    args, 0, stream);
}